// Round 7
// baseline (255.719 us; speedup 1.0000x reference)
//
#include <hip/hip_runtime.h>
#include <hip/hip_bf16.h>
#include <math.h>

// Problem constants
#define D       18
#define KCB     4096       // codebook entries
#define NROW    32768      // 8 * 64 * 64
#define RPB     64         // rows per block (= lanes per wave) in hs_main
#define NWAVE   8          // waves per block; each owns a 512-k slice
#define KSLICE  512        // k's per wave slice
#define NBLK    (NROW / RPB)   // 512 blocks

#define P100     144.26950408889634f   // 100 * log2(e)
#define NEGP100  (-144.26950408889634f)
#define LN2f     0.6931471805599453f
#define INVP100  0.006931471805599453f // 1/P100 = ln2/100

#define Q_OFF   0
#define IDX_OFF 589824               // 8*18*64*64
#define SCL_OFF 622592               // + 32768

// ws layout (in floats):
//   [0..1]   entropy-sum, commit-sum
//   [16..)   kvec (4096)
//   [8192..) An per pixel (32768)
//   [40960..)  X_ext  (32768 x 64 bf16 = 1,048,576 floats)
//   [1089536..) SP_ext (4096 x 64 bf16 = 131,072 floats)
#define WS_SCAL  0
#define WS_KVEC  16
#define WS_AN    8192
#define WS_XEXT  40960
#define WS_SPEXT 1089536

typedef __attribute__((ext_vector_type(8))) short bf16x8;
typedef __attribute__((ext_vector_type(4))) float f32x4;

__device__ __forceinline__ unsigned short f2bf(float f, float& residual)
{
    __hip_bfloat16 b = __float2bfloat16(f);       // RNE
    residual = f - __bfloat162float(b);
    union { __hip_bfloat16 b; unsigned short u; } cv;
    cv.b = b;
    return cv.u;
}

// Build packed extended-K bf16 operands.
// X_ext row (pixel): [h0..h17 | l0..l17 | h0..h17 | 0 x10]   (xs = P100-scaled)
// SP_ext row (k):    [h0..h17 | h0..h17 | l0..l17 | 0 x10]
// Pairing over ext dim gives hh + h'l + l'h per (k,pixel).
__global__ __launch_bounds__(256)
void hs_prep(const float* __restrict__ x, const float* __restrict__ sp,
             unsigned short* __restrict__ xext, unsigned short* __restrict__ spext)
{
    const int tid = threadIdx.x;
    unsigned int hu[18], lu[18];

    if (blockIdx.x < 128) {
        const int pix = blockIdx.x * 256 + tid;
        const int b = pix >> 12, p = pix & 4095;
        float v[D];
        float ss = 0.f;
#pragma unroll
        for (int j = 0; j < D; ++j) {
            float t = x[(b * D + j) * 4096 + p];
            v[j] = t;
            ss += t * t;
        }
        const float sf = (1.0f / sqrtf(ss)) * P100;
#pragma unroll
        for (int j = 0; j < D; ++j) {
            float r;
            hu[j] = f2bf(v[j] * sf, r);
            float r2;
            lu[j] = f2bf(r, r2);
        }
        unsigned int hw[9], lw[9];
#pragma unroll
        for (int i = 0; i < 9; ++i) {
            hw[i] = hu[2 * i] | (hu[2 * i + 1] << 16);
            lw[i] = lu[2 * i] | (lu[2 * i + 1] << 16);
        }
        uint4* dst = (uint4*)(xext + (size_t)pix * 64);
        dst[0] = make_uint4(hw[0], hw[1], hw[2], hw[3]);
        dst[1] = make_uint4(hw[4], hw[5], hw[6], hw[7]);
        dst[2] = make_uint4(hw[8], lw[0], lw[1], lw[2]);
        dst[3] = make_uint4(lw[3], lw[4], lw[5], lw[6]);
        dst[4] = make_uint4(lw[7], lw[8], hw[0], hw[1]);
        dst[5] = make_uint4(hw[2], hw[3], hw[4], hw[5]);
        dst[6] = make_uint4(hw[6], hw[7], hw[8], 0);
        dst[7] = make_uint4(0, 0, 0, 0);
    } else {
        const int k = (blockIdx.x - 128) * 256 + tid;
#pragma unroll
        for (int j = 0; j < D; ++j) {
            float r;
            hu[j] = f2bf(sp[k * D + j], r);
            float r2;
            lu[j] = f2bf(r, r2);
        }
        unsigned int hw[9], lw[9];
#pragma unroll
        for (int i = 0; i < 9; ++i) {
            hw[i] = hu[2 * i] | (hu[2 * i + 1] << 16);
            lw[i] = lu[2 * i] | (lu[2 * i + 1] << 16);
        }
        uint4* dst = (uint4*)(spext + (size_t)k * 64);
        dst[0] = make_uint4(hw[0], hw[1], hw[2], hw[3]);
        dst[1] = make_uint4(hw[4], hw[5], hw[6], hw[7]);
        dst[2] = make_uint4(hw[8], hw[0], hw[1], hw[2]);
        dst[3] = make_uint4(hw[3], hw[4], hw[5], hw[6]);
        dst[4] = make_uint4(hw[7], hw[8], lw[0], lw[1]);
        dst[5] = make_uint4(lw[2], lw[3], lw[4], lw[5]);
        dst[6] = make_uint4(lw[6], lw[7], lw[8], 0);
        dst[7] = make_uint4(0, 0, 0, 0);
    }
}

__global__ __launch_bounds__(512, 4)
void hs_main(const float* __restrict__ x, const float* __restrict__ sp,
             float* __restrict__ out_q, float* __restrict__ out_idx,
             float* __restrict__ ws_scal, float* __restrict__ ws_An)
{
    __shared__ float pm[NWAVE][RPB];      // per-slice max
    __shared__ float pz[NWAVE][RPB];      // per-slice Z
    __shared__ float ps[NWAVE][RPB];      // per-slice S
    __shared__ int   pi[NWAVE][RPB];      // per-slice argmax

    const int tid = threadIdx.x;
    const int l   = tid & 63;                               // lane = row
    const int wu  = __builtin_amdgcn_readfirstlane(tid >> 6);  // wave id
    const int row = blockIdx.x * RPB + l;
    const int b   = row >> 12;
    const int p   = row & 4095;

    // ---- every wave loads & normalizes its lanes' row (redundant, L2-hot) ----
    float xs[D];
    float ss = 0.f;
#pragma unroll
    for (int j = 0; j < D; ++j) {
        float v = x[(b * D + j) * 4096 + p];
        xs[j] = v;
        ss += v * v;
    }
    const float sf = (1.0f / sqrtf(ss)) * P100;
#pragma unroll
    for (int j = 0; j < D; ++j) xs[j] *= sf;

    // ---- pass 1: wave-uniform codebook sweep over this wave's k-slice ----
    const int kbeg = wu * KSLICE;
    float Z = 0.f, S = 0.f, m = -1e30f;
    int idx = kbeg;

#pragma unroll 2
    for (int kk = 0; kk < KSLICE; kk += 2) {
        const float4* k4 = (const float4*)(sp + (kbeg + kk) * D); // 144B pair, 16B-aligned
        float4 q0 = k4[0], q1 = k4[1], q2 = k4[2], q3 = k4[3], q4 = k4[4];
        float4 q5 = k4[5], q6 = k4[6], q7 = k4[7], q8 = k4[8];

        float ta = fmaf(xs[0], q0.x, NEGP100);
        ta = fmaf(xs[1],  q0.y, ta); ta = fmaf(xs[2],  q0.z, ta);
        ta = fmaf(xs[3],  q0.w, ta); ta = fmaf(xs[4],  q1.x, ta);
        ta = fmaf(xs[5],  q1.y, ta); ta = fmaf(xs[6],  q1.z, ta);
        ta = fmaf(xs[7],  q1.w, ta); ta = fmaf(xs[8],  q2.x, ta);
        ta = fmaf(xs[9],  q2.y, ta); ta = fmaf(xs[10], q2.z, ta);
        ta = fmaf(xs[11], q2.w, ta); ta = fmaf(xs[12], q3.x, ta);
        ta = fmaf(xs[13], q3.y, ta); ta = fmaf(xs[14], q3.z, ta);
        ta = fmaf(xs[15], q3.w, ta); ta = fmaf(xs[16], q4.x, ta);
        ta = fmaf(xs[17], q4.y, ta);

        float tb = fmaf(xs[0], q4.z, NEGP100);
        tb = fmaf(xs[1],  q4.w, tb); tb = fmaf(xs[2],  q5.x, tb);
        tb = fmaf(xs[3],  q5.y, tb); tb = fmaf(xs[4],  q5.z, tb);
        tb = fmaf(xs[5],  q5.w, tb); tb = fmaf(xs[6],  q6.x, tb);
        tb = fmaf(xs[7],  q6.y, tb); tb = fmaf(xs[8],  q6.z, tb);
        tb = fmaf(xs[9],  q6.w, tb); tb = fmaf(xs[10], q7.x, tb);
        tb = fmaf(xs[11], q7.y, tb); tb = fmaf(xs[12], q7.z, tb);
        tb = fmaf(xs[13], q7.w, tb); tb = fmaf(xs[14], q8.x, tb);
        tb = fmaf(xs[15], q8.y, tb); tb = fmaf(xs[16], q8.z, tb);
        tb = fmaf(xs[17], q8.w, tb);

        if (ta > m) { m = ta; idx = kbeg + kk; }
        if (tb > m) { m = tb; idx = kbeg + kk + 1; }
        float ea = __builtin_amdgcn_exp2f(ta);
        float eb = __builtin_amdgcn_exp2f(tb);
        Z += ea; S = fmaf(ta, ea, S);
        Z += eb; S = fmaf(tb, eb, S);
    }

    pm[wu][l] = m; pz[wu][l] = Z; ps[wu][l] = S; pi[wu][l] = idx;
    __syncthreads();

    // ---- wave 0: merge 8 slices per row, entropy, q/idx/commit epilogue ----
    if (wu == 0) {
        float mt = pm[0][l], Zt = pz[0][l], St = ps[0][l];
        int   it = pi[0][l];
#pragma unroll
        for (int s = 1; s < NWAVE; ++s) {
            float ms = pm[s][l];
            if (ms > mt) { mt = ms; it = pi[s][l]; }   // ascending slices: first max
            Zt += pz[s][l];
            St += ps[s][l];
        }
        const float l2Z = log2f(Zt);
        const float ent = LN2f * (l2Z - St / Zt);
        ws_An[row] = -(P100 + l2Z);    // pass-2 seed: exp2(P100*s + An)
        out_idx[row] = (float)it;

        // gather chosen codeword once; write q; accumulate commit
        float2 g[9];
        const float2* gr = (const float2*)(sp + it * D);
#pragma unroll
        for (int j = 0; j < 9; ++j) g[j] = gr[j];
        float cp = 0.f;
#pragma unroll
        for (int j = 0; j < 9; ++j) {
            float qx = g[j].x, qy = g[j].y;
            float dx = fmaf(xs[2 * j],     INVP100, -qx);
            float dy = fmaf(xs[2 * j + 1], INVP100, -qy);
            cp = fmaf(dx, dx, cp);
            cp = fmaf(dy, dy, cp);
            out_q[(b * D + 2 * j)     * 4096 + p] = qx;
            out_q[(b * D + 2 * j + 1) * 4096 + p] = qy;
        }

        // wave-reduce entropy & commit over the 64 rows, one atomic each
        float v1 = ent, v2 = cp;
#pragma unroll
        for (int off = 1; off < 64; off <<= 1) {
            v1 += __shfl_xor(v1, off);
            v2 += __shfl_xor(v2, off);
        }
        if (l == 0) {
            atomicAdd(&ws_scal[0], v1);
            atomicAdd(&ws_scal[1], v2);
        }
    }
}

// Pass 2 via MFMA: avg_probs. M-dim = codebook k (16 per wave), N-dim = pixels.
// Wave (ktile, slice): sweeps 2048 pixels in 128 16x16 tiles; per-k partial sums
// stay lane-local (4 regs), reduced across the 16-lane column group at the end.
__global__ __launch_bounds__(256)
void hs_pass2(const unsigned short* __restrict__ xext,
              const unsigned short* __restrict__ spext,
              const float* __restrict__ An, float* __restrict__ kvec)
{
    const int tid = threadIdx.x;
    const int l   = tid & 63;
    const int W   = blockIdx.x * 4 + (tid >> 6);
    const int ktile = W & 255;        // 256 k-tiles of 16
    const int slice = W >> 8;         // 16 pixel slices of 2048
    const int lr = l & 15;
    const int lg = l >> 4;

    // A fragment (codebook side), loop-invariant:
    // lane l holds A[row = lr][ext = lg*8 + j]
    const bf16x8* arow = (const bf16x8*)(spext + ((size_t)(ktile * 16 + lr) * 64 + lg * 8));
    const bf16x8 alo = arow[0];
    const bf16x8 ahi = arow[4];       // ext 32..63

    const unsigned short* xbase = xext + ((size_t)(slice * 2048 + lr) * 64 + lg * 8);
    const float* anbase = An + slice * 2048 + lr;

    float ks0 = 0.f, ks1 = 0.f, ks2 = 0.f, ks3 = 0.f;

#pragma unroll 2
    for (int pt = 0; pt < 128; ++pt) {
        const bf16x8* brow = (const bf16x8*)(xbase + pt * 16 * 64);
        bf16x8 blo = brow[0];
        bf16x8 bhi = brow[4];
        f32x4 c = {0.f, 0.f, 0.f, 0.f};
        c = __builtin_amdgcn_mfma_f32_16x16x32_bf16(alo, blo, c, 0, 0, 0);
        c = __builtin_amdgcn_mfma_f32_16x16x32_bf16(ahi, bhi, c, 0, 0, 0);
        const float an = anbase[pt * 16];
        ks0 += __builtin_amdgcn_exp2f(c[0] + an);
        ks1 += __builtin_amdgcn_exp2f(c[1] + an);
        ks2 += __builtin_amdgcn_exp2f(c[2] + an);
        ks3 += __builtin_amdgcn_exp2f(c[3] + an);
    }

    // reduce across the 16 pixel-columns (lanes with same lg)
#pragma unroll
    for (int off = 1; off < 16; off <<= 1) {
        ks0 += __shfl_xor(ks0, off);
        ks1 += __shfl_xor(ks1, off);
        ks2 += __shfl_xor(ks2, off);
        ks3 += __shfl_xor(ks3, off);
    }
    if (lr == 0) {
        const int k0 = ktile * 16 + lg * 4;
        atomicAdd(&kvec[k0 + 0], ks0);
        atomicAdd(&kvec[k0 + 1], ks1);
        atomicAdd(&kvec[k0 + 2], ks2);
        atomicAdd(&kvec[k0 + 3], ks3);
    }
}

__global__ void hs_final(const float* __restrict__ ws_kvec,
                         const float* __restrict__ ws_scal,
                         float* __restrict__ out)
{
    __shared__ float red[4];
    const int tid = threadIdx.x;
    float local = 0.f;
    for (int k = tid; k < KCB; k += 256) {
        float a = ws_kvec[k] * (1.0f / 32768.0f);
        local += a * (log2f(a + 1e-15f) * LN2f);
    }
#pragma unroll
    for (int off = 1; off < 64; off <<= 1) local += __shfl_xor(local, off);
    if ((tid & 63) == 0) red[tid >> 6] = local;
    __syncthreads();
    if (tid == 0) {
        float mean_entro = -(red[0] + red[1] + red[2] + red[3]);
        float entro_mean = ws_scal[0] * (1.0f / 32768.0f);
        float commit     = ws_scal[1] * (1.0f / (32768.0f * 18.0f));
        out[SCL_OFF + 0] = entro_mean;
        out[SCL_OFF + 1] = mean_entro;
        out[SCL_OFF + 2] = entro_mean - mean_entro;
        out[SCL_OFF + 3] = commit;
    }
}

extern "C" void kernel_launch(void* const* d_in, const int* in_sizes, int n_in,
                              void* d_out, int out_size, void* d_ws, size_t ws_size,
                              hipStream_t stream)
{
    const float* x  = (const float*)d_in[0];
    const float* sp = (const float*)d_in[1];
    float* out = (float*)d_out;
    float* ws  = (float*)d_ws;

    hipMemsetAsync(ws, 0, (WS_KVEC + KCB) * sizeof(float), stream);

    hs_prep<<<144, 256, 0, stream>>>(x, sp,
                                     (unsigned short*)(ws + WS_XEXT),
                                     (unsigned short*)(ws + WS_SPEXT));
    hs_main<<<NBLK, 512, 0, stream>>>(x, sp, out + Q_OFF, out + IDX_OFF,
                                      ws + WS_SCAL, ws + WS_AN);
    hs_pass2<<<1024, 256, 0, stream>>>((const unsigned short*)(ws + WS_XEXT),
                                       (const unsigned short*)(ws + WS_SPEXT),
                                       ws + WS_AN, ws + WS_KVEC);
    hs_final<<<1, 256, 0, stream>>>(ws + WS_KVEC, ws + WS_SCAL, out);
}

// Round 8
// 153.469 us; speedup vs baseline: 1.6663x; 1.6663x over previous
//
#include <hip/hip_runtime.h>
#include <hip/hip_bf16.h>
#include <math.h>

// Problem constants
#define D       18
#define KCB     4096       // codebook entries
#define NROW    32768      // 8 * 64 * 64
#define RPB     64         // rows (pixels) per block = lanes per wave
#define NWAVE   8          // waves per block; each owns a 512-k slice
#define KSLICE  512        // k's per wave slice (pass 1)
#define NBLK    (NROW / RPB)   // 512 blocks

#define P100     144.26950408889634f   // 100 * log2(e)
#define NEGP100  (-144.26950408889634f)
#define LN2f     0.6931471805599453f
#define INVP100  0.006931471805599453f // 1/P100 = ln2/100

#define Q_OFF   0
#define IDX_OFF 589824               // 8*18*64*64
#define SCL_OFF 622592               // + 32768

// ws layout (floats):
//   [0..1]      entropy-sum, commit-sum
//   [16..)      kvec (4096)
//   [8192..)    SP_ext tiled A-fragments (4096 k x 32B = 131072 floats)
//   [139264..)  per-block kvec partials (512 x 4096 = 2097152 floats)
#define WS_SCAL  0
#define WS_KVEC  16
#define WS_SPEXT 8192
#define WS_PART  139264
#define WS_END   (WS_PART + NBLK * KCB)

typedef __attribute__((ext_vector_type(8))) short bf16x8;
typedef __attribute__((ext_vector_type(4))) float f32x4;

__device__ __forceinline__ unsigned int f2bf(float f, float& residual)
{
    __hip_bfloat16 b = __float2bfloat16(f);       // RNE
    residual = f - __bfloat162float(b);
    union { __hip_bfloat16 b; unsigned short u; } cv;
    cv.b = b;
    return (unsigned int)cv.u;
}

// Precompute codebook A-fragments, MFMA-tile-contiguous.
// SP ext row (64 bf16): [h0..h17 | h0..h17 | l0..l17 | 0 x10]
// Tiled record: for k-tile kt, lane l = g*16 + r holds row (kt*16+r),
// ext chunk [g*8 .. g*8+8) (alo) and [32+g*8 .. +8) (ahi): 32 B per lane.
__global__ __launch_bounds__(256)
void hs_prep(const float* __restrict__ sp, unsigned int* __restrict__ spx)
{
    const int k  = blockIdx.x * 256 + threadIdx.x;   // 16 blocks x 256 = 4096
    const int kt = k >> 4, r = k & 15;
    unsigned int hu[18], lu[18];
#pragma unroll
    for (int j = 0; j < D; ++j) {
        float res, res2;
        hu[j] = f2bf(sp[k * D + j], res);
        lu[j] = f2bf(res, res2);
    }
    unsigned int w[32];
#pragma unroll
    for (int i = 0; i < 9; ++i) {
        unsigned int hwv = hu[2 * i] | (hu[2 * i + 1] << 16);
        unsigned int lwv = lu[2 * i] | (lu[2 * i + 1] << 16);
        w[i] = hwv; w[9 + i] = hwv; w[18 + i] = lwv;
    }
#pragma unroll
    for (int i = 27; i < 32; ++i) w[i] = 0;
#pragma unroll
    for (int g = 0; g < 4; ++g) {
        unsigned int* dst = spx + (size_t)kt * 512 + (g * 16 + r) * 8;
        *(uint4*)(dst)     = make_uint4(w[g*4], w[g*4+1], w[g*4+2], w[g*4+3]);
        *(uint4*)(dst + 4) = make_uint4(w[16+g*4], w[16+g*4+1], w[16+g*4+2], w[16+g*4+3]);
    }
}

__global__ __launch_bounds__(512, 4)
void hs_main(const float* __restrict__ x, const float* __restrict__ sp,
             float* __restrict__ out_q, float* __restrict__ out_idx,
             float* __restrict__ ws_scal, const unsigned int* __restrict__ spx,
             float* __restrict__ ws_part, float* __restrict__ ws_kvec)
{
    __shared__ float pm[NWAVE][RPB];         // per-slice max
    __shared__ float pz[NWAVE][RPB];         // per-slice Z
    __shared__ float ps[NWAVE][RPB];         // per-slice S
    __shared__ int   pi[NWAVE][RPB];         // per-slice argmax
    __shared__ float An_lds[RPB];            // -(P100 + log2 Z)
    __shared__ unsigned int xe[RPB][36];     // pixel ext rows (144B padded)

    const int tid = threadIdx.x;
    const int l   = tid & 63;                               // lane = pixel row
    const int wu  = __builtin_amdgcn_readfirstlane(tid >> 6);  // wave id
    const int row = blockIdx.x * RPB + l;
    const int b   = row >> 12;
    const int p   = row & 4095;

    // ---- every wave loads & normalizes its lanes' row (redundant, L2-hot) ----
    float xs[D];
    float ss = 0.f;
#pragma unroll
    for (int j = 0; j < D; ++j) {
        float v = x[(b * D + j) * 4096 + p];
        xs[j] = v;
        ss += v * v;
    }
    const float sf = (1.0f / sqrtf(ss)) * P100;
#pragma unroll
    for (int j = 0; j < D; ++j) xs[j] *= sf;

    // ---- pass 1: wave-uniform codebook sweep (unchanged, verified) ----
    const int kbeg = wu * KSLICE;
    float Z = 0.f, S = 0.f, m = -1e30f;
    int idx = kbeg;

#pragma unroll 2
    for (int kk = 0; kk < KSLICE; kk += 2) {
        const float4* k4 = (const float4*)(sp + (kbeg + kk) * D); // 144B pair
        float4 q0 = k4[0], q1 = k4[1], q2 = k4[2], q3 = k4[3], q4 = k4[4];
        float4 q5 = k4[5], q6 = k4[6], q7 = k4[7], q8 = k4[8];

        float ta = fmaf(xs[0], q0.x, NEGP100);
        ta = fmaf(xs[1],  q0.y, ta); ta = fmaf(xs[2],  q0.z, ta);
        ta = fmaf(xs[3],  q0.w, ta); ta = fmaf(xs[4],  q1.x, ta);
        ta = fmaf(xs[5],  q1.y, ta); ta = fmaf(xs[6],  q1.z, ta);
        ta = fmaf(xs[7],  q1.w, ta); ta = fmaf(xs[8],  q2.x, ta);
        ta = fmaf(xs[9],  q2.y, ta); ta = fmaf(xs[10], q2.z, ta);
        ta = fmaf(xs[11], q2.w, ta); ta = fmaf(xs[12], q3.x, ta);
        ta = fmaf(xs[13], q3.y, ta); ta = fmaf(xs[14], q3.z, ta);
        ta = fmaf(xs[15], q3.w, ta); ta = fmaf(xs[16], q4.x, ta);
        ta = fmaf(xs[17], q4.y, ta);

        float tb = fmaf(xs[0], q4.z, NEGP100);
        tb = fmaf(xs[1],  q4.w, tb); tb = fmaf(xs[2],  q5.x, tb);
        tb = fmaf(xs[3],  q5.y, tb); tb = fmaf(xs[4],  q5.z, tb);
        tb = fmaf(xs[5],  q5.w, tb); tb = fmaf(xs[6],  q6.x, tb);
        tb = fmaf(xs[7],  q6.y, tb); tb = fmaf(xs[8],  q6.z, tb);
        tb = fmaf(xs[9],  q6.w, tb); tb = fmaf(xs[10], q7.x, tb);
        tb = fmaf(xs[11], q7.y, tb); tb = fmaf(xs[12], q7.z, tb);
        tb = fmaf(xs[13], q7.w, tb); tb = fmaf(xs[14], q8.x, tb);
        tb = fmaf(xs[15], q8.y, tb); tb = fmaf(xs[16], q8.z, tb);
        tb = fmaf(xs[17], q8.w, tb);

        if (ta > m) { m = ta; idx = kbeg + kk; }
        if (tb > m) { m = tb; idx = kbeg + kk + 1; }
        float ea = __builtin_amdgcn_exp2f(ta);
        float eb = __builtin_amdgcn_exp2f(tb);
        Z += ea; S = fmaf(ta, ea, S);
        Z += eb; S = fmaf(tb, eb, S);
    }

    pm[wu][l] = m; pz[wu][l] = Z; ps[wu][l] = S; pi[wu][l] = idx;

    // ---- wave 1: build pixel ext rows in LDS (X side: [h | l | h | pad]) ----
    if (wu == 1) {
        unsigned int hu[18], lu[18];
#pragma unroll
        for (int j = 0; j < D; ++j) {
            float res, res2;
            hu[j] = f2bf(xs[j], res);
            lu[j] = f2bf(res, res2);
        }
#pragma unroll
        for (int i = 0; i < 9; ++i) {
            unsigned int hwv = hu[2 * i] | (hu[2 * i + 1] << 16);
            unsigned int lwv = lu[2 * i] | (lu[2 * i + 1] << 16);
            xe[l][i] = hwv; xe[l][9 + i] = lwv; xe[l][18 + i] = hwv;
        }
#pragma unroll
        for (int i = 27; i < 32; ++i) xe[l][i] = 0;
    }
    __syncthreads();

    // ---- wave 0: merge 8 slices per row, entropy, q/idx/commit epilogue ----
    if (wu == 0) {
        float mt = pm[0][l], Zt = pz[0][l], St = ps[0][l];
        int   it = pi[0][l];
#pragma unroll
        for (int s = 1; s < NWAVE; ++s) {
            float ms = pm[s][l];
            if (ms > mt) { mt = ms; it = pi[s][l]; }   // ascending: first max
            Zt += pz[s][l];
            St += ps[s][l];
        }
        const float l2Z = log2f(Zt);
        const float ent = LN2f * (l2Z - St / Zt);
        An_lds[l] = -(P100 + l2Z);
        out_idx[row] = (float)it;

        float2 g[9];
        const float2* gr = (const float2*)(sp + it * D);
#pragma unroll
        for (int j = 0; j < 9; ++j) g[j] = gr[j];
        float cp = 0.f;
#pragma unroll
        for (int j = 0; j < 9; ++j) {
            float qx = g[j].x, qy = g[j].y;
            float dx = fmaf(xs[2 * j],     INVP100, -qx);
            float dy = fmaf(xs[2 * j + 1], INVP100, -qy);
            cp = fmaf(dx, dx, cp);
            cp = fmaf(dy, dy, cp);
            out_q[(b * D + 2 * j)     * 4096 + p] = qx;
            out_q[(b * D + 2 * j + 1) * 4096 + p] = qy;
        }

        float v1 = ent, v2 = cp;
#pragma unroll
        for (int off = 1; off < 64; off <<= 1) {
            v1 += __shfl_xor(v1, off);
            v2 += __shfl_xor(v2, off);
        }
        if (l == 0) {
            atomicAdd(&ws_scal[0], v1);
            atomicAdd(&ws_scal[1], v2);
        }
    }
    __syncthreads();   // publish An_lds (xe published at previous barrier)

    // ---- pass 2 (fused, MFMA): block's 64 pixels x all 4096 k ----
    const int col = l & 15, g = l >> 4;
    union { uint4 u; bf16x8 b; } cv0, cv1;
    bf16x8 blo[4], bhi[4];
    float an[4];
#pragma unroll
    for (int pt = 0; pt < 4; ++pt) {
        const int pix = pt * 16 + col;
        cv0.u = *(const uint4*)&xe[pix][g * 4];      blo[pt] = cv0.b;
        cv1.u = *(const uint4*)&xe[pix][16 + g * 4]; bhi[pt] = cv1.b;
        an[pt] = An_lds[pix];
    }

    float* pdst = ws_part ? ws_part + (size_t)blockIdx.x * KCB : nullptr;
    const int kt0 = wu * 32;    // 32 k-tiles of 16 per wave
#pragma unroll 2
    for (int kt = 0; kt < 32; ++kt) {
        const uint4* ap = (const uint4*)(spx + (size_t)(kt0 + kt) * 512 + l * 8);
        cv0.u = ap[0];           // alo: coalesced 16B/lane
        cv1.u = ap[1];           // ahi
        const bf16x8 alo = cv0.b, ahi = cv1.b;

        float ks0 = 0.f, ks1 = 0.f, ks2 = 0.f, ks3 = 0.f;
#pragma unroll
        for (int pt = 0; pt < 4; ++pt) {
            f32x4 c = {0.f, 0.f, 0.f, 0.f};
            c = __builtin_amdgcn_mfma_f32_16x16x32_bf16(alo, blo[pt], c, 0, 0, 0);
            c = __builtin_amdgcn_mfma_f32_16x16x32_bf16(ahi, bhi[pt], c, 0, 0, 0);
            ks0 += __builtin_amdgcn_exp2f(c[0] + an[pt]);
            ks1 += __builtin_amdgcn_exp2f(c[1] + an[pt]);
            ks2 += __builtin_amdgcn_exp2f(c[2] + an[pt]);
            ks3 += __builtin_amdgcn_exp2f(c[3] + an[pt]);
        }
#pragma unroll
        for (int off = 1; off < 16; off <<= 1) {
            ks0 += __shfl_xor(ks0, off);
            ks1 += __shfl_xor(ks1, off);
            ks2 += __shfl_xor(ks2, off);
            ks3 += __shfl_xor(ks3, off);
        }
        if (col == 0) {
            const int kk = (kt0 + kt) * 16 + g * 4;
            if (pdst) {
                *(float4*)(pdst + kk) = make_float4(ks0, ks1, ks2, ks3);
            } else {
                atomicAdd(&ws_kvec[kk + 0], ks0);
                atomicAdd(&ws_kvec[kk + 1], ks1);
                atomicAdd(&ws_kvec[kk + 2], ks2);
                atomicAdd(&ws_kvec[kk + 3], ks3);
            }
        }
    }
}

// Reduce NBLK x KCB partials into kvec. Grid 256: kb = 16 k-slabs x sb = 16
// slabs of 32 blocks; 16 atomics per k.
__global__ void hs_reduce(const float* __restrict__ part, float* __restrict__ kvec)
{
    const int kb = blockIdx.x & 15;
    const int sb = blockIdx.x >> 4;
    const int k  = kb * 256 + threadIdx.x;
    const float* pp = part + (size_t)sb * 32 * KCB + k;
    float s = 0.f;
#pragma unroll 8
    for (int bb = 0; bb < 32; ++bb) s += pp[bb * KCB];
    atomicAdd(&kvec[k], s);
}

__global__ void hs_final(const float* __restrict__ ws_kvec,
                         const float* __restrict__ ws_scal,
                         float* __restrict__ out)
{
    __shared__ float red[4];
    const int tid = threadIdx.x;
    float local = 0.f;
    for (int k = tid; k < KCB; k += 256) {
        float a = ws_kvec[k] * (1.0f / 32768.0f);
        local += a * (log2f(a + 1e-15f) * LN2f);
    }
#pragma unroll
    for (int off = 1; off < 64; off <<= 1) local += __shfl_xor(local, off);
    if ((tid & 63) == 0) red[tid >> 6] = local;
    __syncthreads();
    if (tid == 0) {
        float mean_entro = -(red[0] + red[1] + red[2] + red[3]);
        float entro_mean = ws_scal[0] * (1.0f / 32768.0f);
        float commit     = ws_scal[1] * (1.0f / (32768.0f * 18.0f));
        out[SCL_OFF + 0] = entro_mean;
        out[SCL_OFF + 1] = mean_entro;
        out[SCL_OFF + 2] = entro_mean - mean_entro;
        out[SCL_OFF + 3] = commit;
    }
}

extern "C" void kernel_launch(void* const* d_in, const int* in_sizes, int n_in,
                              void* d_out, int out_size, void* d_ws, size_t ws_size,
                              hipStream_t stream)
{
    const float* x  = (const float*)d_in[0];
    const float* sp = (const float*)d_in[1];
    float* out = (float*)d_out;
    float* ws  = (float*)d_ws;

    const bool partials = ws_size >= (size_t)WS_END * sizeof(float);

    hipMemsetAsync(ws, 0, (WS_KVEC + KCB) * sizeof(float), stream);

    hs_prep<<<16, 256, 0, stream>>>(sp, (unsigned int*)(ws + WS_SPEXT));
    hs_main<<<NBLK, 512, 0, stream>>>(x, sp, out + Q_OFF, out + IDX_OFF,
                                      ws + WS_SCAL,
                                      (const unsigned int*)(ws + WS_SPEXT),
                                      partials ? ws + WS_PART : nullptr,
                                      ws + WS_KVEC);
    if (partials)
        hs_reduce<<<256, 256, 0, stream>>>(ws + WS_PART, ws + WS_KVEC);
    hs_final<<<1, 256, 0, stream>>>(ws + WS_KVEC, ws + WS_SCAL, out);
}

// Round 9
// 118.759 us; speedup vs baseline: 2.1533x; 1.2923x over previous
//
#include <hip/hip_runtime.h>
#include <hip/hip_bf16.h>
#include <math.h>

// Problem constants
#define D       18
#define KCB     4096       // codebook entries
#define NROW    32768      // 8 * 64 * 64
#define RPB     64         // pixels per block = lanes per wave
#define NWAVE   8          // waves per block; each owns 512 k (32 tiles of 16)
#define KTPW    32         // k-tiles per wave
#define NBLK    (NROW / RPB)   // 512 blocks

#define P100     144.26950408889634f   // 100 * log2(e)
#define NEGP100  (-144.26950408889634f)
#define LN2f     0.6931471805599453f
#define INVP100  0.006931471805599453f // 1/P100
#define DELTA    0.01f                 // argmax recheck window (t-units), ~20x err bound

#define Q_OFF   0
#define IDX_OFF 589824               // 8*18*64*64
#define SCL_OFF 622592               // + 32768

// ws layout (floats):
//   [0..1]      entropy-sum, commit-sum
//   [16..)      kvec (4096)
//   [8192..)    SP_ext tiled A-fragments (4096 k x 128B = 131072 floats)
//   [139264..)  per-block kvec partials (512 x 4096)
#define WS_SCAL  0
#define WS_KVEC  16
#define WS_SPEXT 8192
#define WS_PART  139264
#define WS_END   (WS_PART + NBLK * KCB)

typedef __attribute__((ext_vector_type(8))) short bf16x8;
typedef __attribute__((ext_vector_type(4))) float f32x4;

// merge top-2 candidate sets (value desc, index tie-break = lower wins)
#define TOP2_MERGE(m1, i1, m2, i2, om1, oi1, om2, oi2) do {            \
    bool _bw = ((om1) > (m1)) || ((om1) == (m1) && (oi1) < (i1));      \
    float _lv = _bw ? (m1) : (om1); int _li = _bw ? (i1) : (oi1);      \
    float _ov = _bw ? (om2) : (m2); int _oi = _bw ? (oi2) : (i2);      \
    float _w1 = _bw ? (om1) : (m1); int _wi = _bw ? (oi1) : (i1);      \
    bool _b2 = (_ov > _lv) || (_ov == _lv && _oi < _li);               \
    (m2) = _b2 ? _ov : _lv; (i2) = _b2 ? _oi : _li;                    \
    (m1) = _w1; (i1) = _wi;                                            \
} while (0)

__device__ __forceinline__ unsigned int f2bf(float f, float& residual)
{
    __hip_bfloat16 b = __float2bfloat16(f);       // RNE
    residual = f - __bfloat162float(b);
    union { __hip_bfloat16 b; unsigned short u; } cv;
    cv.b = b;
    return (unsigned int)cv.u;
}

// Precompute codebook fragments, MFMA-tile-contiguous (verified r8).
// SP ext row (64 bf16): [h0..h17 | h0..h17 | l0..l17 | 0 x10]
// Record: k-tile kt, lane l = g*16 + r holds sp-row (kt*16+r), ext chunks
// [g*8..+8) and [32+g*8..+8): 32B per lane.
__global__ __launch_bounds__(256)
void hs_prep(const float* __restrict__ sp, unsigned int* __restrict__ spx)
{
    const int k  = blockIdx.x * 256 + threadIdx.x;   // 16 blocks x 256 = 4096
    const int kt = k >> 4, r = k & 15;
    unsigned int hu[18], lu[18];
#pragma unroll
    for (int j = 0; j < D; ++j) {
        float res, res2;
        hu[j] = f2bf(sp[k * D + j], res);
        lu[j] = f2bf(res, res2);
    }
    unsigned int w[32];
#pragma unroll
    for (int i = 0; i < 9; ++i) {
        unsigned int hwv = hu[2 * i] | (hu[2 * i + 1] << 16);
        unsigned int lwv = lu[2 * i] | (lu[2 * i + 1] << 16);
        w[i] = hwv; w[9 + i] = hwv; w[18 + i] = lwv;
    }
#pragma unroll
    for (int i = 27; i < 32; ++i) w[i] = 0;
#pragma unroll
    for (int g = 0; g < 4; ++g) {
        unsigned int* dst = spx + (size_t)kt * 512 + (g * 16 + r) * 8;
        *(uint4*)(dst)     = make_uint4(w[g*4], w[g*4+1], w[g*4+2], w[g*4+3]);
        *(uint4*)(dst + 4) = make_uint4(w[16+g*4], w[16+g*4+1], w[16+g*4+2], w[16+g*4+3]);
    }
}

__global__ __launch_bounds__(512, 4)
void hs_main(const float* __restrict__ x, const float* __restrict__ sp,
             float* __restrict__ out_q, float* __restrict__ out_idx,
             float* __restrict__ ws_scal, const unsigned int* __restrict__ spx,
             float* __restrict__ ws_part, float* __restrict__ ws_kvec)
{
    __shared__ unsigned int xe[RPB][36];     // pixel ext rows [h|l|h|0], 144B stride
    __shared__ float zw[NWAVE][RPB], sw[NWAVE][RPB];
    __shared__ float m1w[NWAVE][RPB], m2w[NWAVE][RPB];
    __shared__ int   i1w[NWAVE][RPB], i2w[NWAVE][RPB];
    __shared__ float An_lds[RPB];            // -(P100 + log2 Z)

    const int tid = threadIdx.x;
    const int l   = tid & 63;                                  // lane
    const int wu  = __builtin_amdgcn_readfirstlane(tid >> 6);  // wave id
    const int col = l & 15, g = l >> 4;
    const int row = blockIdx.x * RPB + l;
    const int b   = row >> 12;
    const int p   = row & 4095;

    // ---- wave 0: load+normalize x rows (P100-scaled) and build xe in LDS ----
    float xs[D];
    if (wu == 0) {
        float ssq = 0.f;
#pragma unroll
        for (int j = 0; j < D; ++j) {
            float v = x[(b * D + j) * 4096 + p];
            xs[j] = v;
            ssq += v * v;
        }
        const float sf = (1.0f / sqrtf(ssq)) * P100;
#pragma unroll
        for (int j = 0; j < D; ++j) xs[j] *= sf;

        unsigned int hu[18], lu[18];
#pragma unroll
        for (int j = 0; j < D; ++j) {
            float res, res2;
            hu[j] = f2bf(xs[j], res);
            lu[j] = f2bf(res, res2);
        }
#pragma unroll
        for (int i = 0; i < 9; ++i) {
            unsigned int hwv = hu[2 * i] | (hu[2 * i + 1] << 16);
            unsigned int lwv = lu[2 * i] | (lu[2 * i + 1] << 16);
            xe[l][i] = hwv; xe[l][9 + i] = lwv; xe[l][18 + i] = hwv;
        }
#pragma unroll
        for (int i = 27; i < 32; ++i) xe[l][i] = 0;
    }
    __syncthreads();

    // ---- load loop-invariant X fragments (shared by both sweeps) ----
    union { uint4 u; bf16x8 v; } cv;
    bf16x8 fxlo[4], fxhi[4];
#pragma unroll
    for (int pt = 0; pt < 4; ++pt) {
        cv.u = *(const uint4*)&xe[pt * 16 + col][g * 4];      fxlo[pt] = cv.v;
        cv.u = *(const uint4*)&xe[pt * 16 + col][16 + g * 4]; fxhi[pt] = cv.v;
    }

    // ---- sweep 1 (MFMA): t = P100*s - P100; top-2 + Z + S per pixel ----
    float Zp[4] = {0.f, 0.f, 0.f, 0.f};
    float Sp[4] = {0.f, 0.f, 0.f, 0.f};
    float m1p[4] = {-1e30f, -1e30f, -1e30f, -1e30f};
    float m2p[4] = {-1e30f, -1e30f, -1e30f, -1e30f};
    int i1p[4] = {0, 0, 0, 0};
    int i2p[4] = {0, 0, 0, 0};
    const int kof = g * 4;
    const int kt0 = wu * KTPW;

#pragma unroll 2
    for (int kt = 0; kt < KTPW; ++kt) {
        const uint4* ap = (const uint4*)(spx + (size_t)(kt0 + kt) * 512 + l * 8);
        cv.u = ap[0]; const bf16x8 alo = cv.v;
        cv.u = ap[1]; const bf16x8 ahi = cv.v;
        const int ktbase = (kt0 + kt) * 16;
#pragma unroll
        for (int pt = 0; pt < 4; ++pt) {
            f32x4 c = {NEGP100, NEGP100, NEGP100, NEGP100};
            c = __builtin_amdgcn_mfma_f32_16x16x32_bf16(alo, fxlo[pt], c, 0, 0, 0);
            c = __builtin_amdgcn_mfma_f32_16x16x32_bf16(ahi, fxhi[pt], c, 0, 0, 0);
#pragma unroll
            for (int r = 0; r < 4; ++r) {
                const float t = c[r];
                const int k = ktbase + kof + r;
                const bool c1 = t > m1p[pt];
                const bool c2 = t > m2p[pt];
                i2p[pt] = c1 ? i1p[pt] : (c2 ? k : i2p[pt]);
                m2p[pt] = fmaxf(m2p[pt], fminf(m1p[pt], t));
                i1p[pt] = c1 ? k : i1p[pt];
                m1p[pt] = fmaxf(m1p[pt], t);
                const float e = __builtin_amdgcn_exp2f(t);
                Zp[pt] += e;
                Sp[pt] = fmaf(t, e, Sp[pt]);
            }
        }
    }

    // merge across the 4 g-groups (lanes col, col+16, col+32, col+48)
#pragma unroll
    for (int off = 16; off < 64; off <<= 1) {
#pragma unroll
        for (int pt = 0; pt < 4; ++pt) {
            float oZ = __shfl_xor(Zp[pt], off);
            float oS = __shfl_xor(Sp[pt], off);
            float om1 = __shfl_xor(m1p[pt], off);
            float om2 = __shfl_xor(m2p[pt], off);
            int oi1 = __shfl_xor(i1p[pt], off);
            int oi2 = __shfl_xor(i2p[pt], off);
            Zp[pt] += oZ;
            Sp[pt] += oS;
            TOP2_MERGE(m1p[pt], i1p[pt], m2p[pt], i2p[pt], om1, oi1, om2, oi2);
        }
    }
    if (g == 0) {
#pragma unroll
        for (int pt = 0; pt < 4; ++pt) {
            const int px = pt * 16 + col;
            zw[wu][px] = Zp[pt];  sw[wu][px] = Sp[pt];
            m1w[wu][px] = m1p[pt]; m2w[wu][px] = m2p[pt];
            i1w[wu][px] = i1p[pt]; i2w[wu][px] = i2p[pt];
        }
    }
    __syncthreads();

    // ---- wave 0: cross-wave merge + recheck + epilogue ----
    if (wu == 0) {
        float Zt = zw[0][l], St = sw[0][l];
        float m1 = m1w[0][l], m2 = m2w[0][l];
        int i1 = i1w[0][l], i2 = i2w[0][l];
#pragma unroll
        for (int s = 1; s < NWAVE; ++s) {
            Zt += zw[s][l];
            St += sw[s][l];
            float om1 = m1w[s][l], om2 = m2w[s][l];
            int oi1 = i1w[s][l], oi2 = i2w[s][l];
            TOP2_MERGE(m1, i1, m2, i2, om1, oi1, om2, oi2);
        }
        const float l2Z = log2f(Zt);
        const float ent = LN2f * (l2Z - St / Zt);
        An_lds[l] = -(P100 + l2Z);

        int it = i1;
        if (m1 - m2 < DELTA) {   // exact fp32 recheck of the two candidates
            const float2* r1 = (const float2*)(sp + i1 * D);
            const float2* r2 = (const float2*)(sp + i2 * D);
            float d1 = 0.f, d2 = 0.f;
#pragma unroll
            for (int j = 0; j < 9; ++j) {
                d1 = fmaf(xs[2 * j], r1[j].x, d1);
                d1 = fmaf(xs[2 * j + 1], r1[j].y, d1);
                d2 = fmaf(xs[2 * j], r2[j].x, d2);
                d2 = fmaf(xs[2 * j + 1], r2[j].y, d2);
            }
            if (d2 > d1 || (d2 == d1 && i2 < i1)) it = i2;
        }
        out_idx[row] = (float)it;

        // gather chosen codeword (exact fp32); write q; commitment partial
        float2 gq[9];
        const float2* gr = (const float2*)(sp + it * D);
#pragma unroll
        for (int j = 0; j < 9; ++j) gq[j] = gr[j];
        float cp = 0.f;
#pragma unroll
        for (int j = 0; j < 9; ++j) {
            float qx = gq[j].x, qy = gq[j].y;
            float dx = fmaf(xs[2 * j],     INVP100, -qx);
            float dy = fmaf(xs[2 * j + 1], INVP100, -qy);
            cp = fmaf(dx, dx, cp);
            cp = fmaf(dy, dy, cp);
            out_q[(b * D + 2 * j)     * 4096 + p] = qx;
            out_q[(b * D + 2 * j + 1) * 4096 + p] = qy;
        }

        float v1 = ent, v2 = cp;
#pragma unroll
        for (int off = 1; off < 64; off <<= 1) {
            v1 += __shfl_xor(v1, off);
            v2 += __shfl_xor(v2, off);
        }
        if (l == 0) {
            atomicAdd(&ws_scal[0], v1);
            atomicAdd(&ws_scal[1], v2);
        }
    }
    __syncthreads();   // publish An_lds

    // ---- sweep 2 (MFMA, roles swapped: C rows = pixels, cols = k) ----
    float4 an4[4];
#pragma unroll
    for (int pt = 0; pt < 4; ++pt)
        an4[pt] = *(const float4*)&An_lds[pt * 16 + kof];

    float* pdst = ws_part ? ws_part + (size_t)blockIdx.x * KCB : nullptr;
#pragma unroll 2
    for (int kt = 0; kt < KTPW; ++kt) {
        const uint4* ap = (const uint4*)(spx + (size_t)(kt0 + kt) * 512 + l * 8);
        cv.u = ap[0]; const bf16x8 alo = cv.v;
        cv.u = ap[1]; const bf16x8 ahi = cv.v;

        float ksum = 0.f;
#pragma unroll
        for (int pt = 0; pt < 4; ++pt) {
            f32x4 c = {an4[pt].x, an4[pt].y, an4[pt].z, an4[pt].w};
            c = __builtin_amdgcn_mfma_f32_16x16x32_bf16(fxlo[pt], alo, c, 0, 0, 0);
            c = __builtin_amdgcn_mfma_f32_16x16x32_bf16(fxhi[pt], ahi, c, 0, 0, 0);
            ksum += __builtin_amdgcn_exp2f(c[0]);
            ksum += __builtin_amdgcn_exp2f(c[1]);
            ksum += __builtin_amdgcn_exp2f(c[2]);
            ksum += __builtin_amdgcn_exp2f(c[3]);
        }
        ksum += __shfl_xor(ksum, 16);
        ksum += __shfl_xor(ksum, 32);
        if (g == 0) {
            const int kk = (kt0 + kt) * 16 + col;
            if (pdst) pdst[kk] = ksum;
            else      atomicAdd(&ws_kvec[kk], ksum);
        }
    }
}

// Reduce NBLK x KCB partials into kvec (verified r5+).
__global__ void hs_reduce(const float* __restrict__ part, float* __restrict__ kvec)
{
    const int kb = blockIdx.x & 15;
    const int sb = blockIdx.x >> 4;
    const int k  = kb * 256 + threadIdx.x;
    const float* pp = part + (size_t)sb * 32 * KCB + k;
    float s = 0.f;
#pragma unroll 8
    for (int bb = 0; bb < 32; ++bb) s += pp[bb * KCB];
    atomicAdd(&kvec[k], s);
}

__global__ void hs_final(const float* __restrict__ ws_kvec,
                         const float* __restrict__ ws_scal,
                         float* __restrict__ out)
{
    __shared__ float red[4];
    const int tid = threadIdx.x;
    float local = 0.f;
    for (int k = tid; k < KCB; k += 256) {
        float a = ws_kvec[k] * (1.0f / 32768.0f);
        local += a * (log2f(a + 1e-15f) * LN2f);
    }
#pragma unroll
    for (int off = 1; off < 64; off <<= 1) local += __shfl_xor(local, off);
    if ((tid & 63) == 0) red[tid >> 6] = local;
    __syncthreads();
    if (tid == 0) {
        float mean_entro = -(red[0] + red[1] + red[2] + red[3]);
        float entro_mean = ws_scal[0] * (1.0f / 32768.0f);
        float commit     = ws_scal[1] * (1.0f / (32768.0f * 18.0f));
        out[SCL_OFF + 0] = entro_mean;
        out[SCL_OFF + 1] = mean_entro;
        out[SCL_OFF + 2] = entro_mean - mean_entro;
        out[SCL_OFF + 3] = commit;
    }
}

extern "C" void kernel_launch(void* const* d_in, const int* in_sizes, int n_in,
                              void* d_out, int out_size, void* d_ws, size_t ws_size,
                              hipStream_t stream)
{
    const float* x  = (const float*)d_in[0];
    const float* sp = (const float*)d_in[1];
    float* out = (float*)d_out;
    float* ws  = (float*)d_ws;

    const bool partials = ws_size >= (size_t)WS_END * sizeof(float);

    hipMemsetAsync(ws, 0, (WS_KVEC + KCB) * sizeof(float), stream);

    hs_prep<<<16, 256, 0, stream>>>(sp, (unsigned int*)(ws + WS_SPEXT));
    hs_main<<<NBLK, 512, 0, stream>>>(x, sp, out + Q_OFF, out + IDX_OFF,
                                      ws + WS_SCAL,
                                      (const unsigned int*)(ws + WS_SPEXT),
                                      partials ? ws + WS_PART : nullptr,
                                      ws + WS_KVEC);
    if (partials)
        hs_reduce<<<256, 256, 0, stream>>>(ws + WS_PART, ws + WS_KVEC);
    hs_final<<<1, 256, 0, stream>>>(ws + WS_KVEC, ws + WS_SCAL, out);
}

// Round 10
// 81.104 us; speedup vs baseline: 3.1530x; 1.4643x over previous
//
#include <hip/hip_runtime.h>
#include <hip/hip_bf16.h>
#include <math.h>

// Problem constants
#define D       18
#define KCB     4096       // codebook entries
#define NROW    32768      // 8 * 64 * 64
#define RPB     64         // pixels per block = lanes per wave
#define NWAVE   8          // waves per block; each owns 512 k (32 tiles of 16)
#define KTPW    32         // k-tiles per wave
#define NBLK    (NROW / RPB)   // 512 blocks

#define P100     144.26950408889634f   // 100 * log2(e)
#define SEED1    (-152.26950408889634f) // -(P100 + 8): keeps all t strictly < 0
#define LN2f     0.6931471805599453f
#define INVP100  0.006931471805599453f // 1/P100
#define DELTA    0.25f                 // recheck window (t-units): covers 2x key
                                       // quantization (0.0625) + split error

#define Q_OFF   0
#define IDX_OFF 589824               // 8*18*64*64
#define SCL_OFF 622592               // + 32768

// ws layout (floats):
//   [0..1]      E-sum (sum e*t2), commit-sum
//   [16..)      kvec (4096)
//   [8192..)    SP_ext tiled A-fragments (4096 k x 128B = 131072 floats)
//   [139264..)  per-block kvec partials (512 x 4096)
#define WS_SCAL  0
#define WS_KVEC  16
#define WS_SPEXT 8192
#define WS_PART  139264
#define WS_END   (WS_PART + NBLK * KCB)

typedef __attribute__((ext_vector_type(8))) short bf16x8;
typedef __attribute__((ext_vector_type(4))) float f32x4;

__device__ __forceinline__ unsigned int f2bf(float f, float& residual)
{
    __hip_bfloat16 b = __float2bfloat16(f);       // RNE
    residual = f - __bfloat162float(b);
    union { __hip_bfloat16 b; unsigned short u; } cv;
    cv.b = b;
    return (unsigned int)cv.u;
}

// Precompute codebook fragments, MFMA-tile-contiguous (verified r8/r9).
// SP ext row (64 bf16): [h0..h17 | h0..h17 | l0..l17 | 0 x10]
__global__ __launch_bounds__(256)
void hs_prep(const float* __restrict__ sp, unsigned int* __restrict__ spx)
{
    const int k  = blockIdx.x * 256 + threadIdx.x;   // 16 blocks x 256 = 4096
    const int kt = k >> 4, r = k & 15;
    unsigned int hu[18], lu[18];
#pragma unroll
    for (int j = 0; j < D; ++j) {
        float res, res2;
        hu[j] = f2bf(sp[k * D + j], res);
        lu[j] = f2bf(res, res2);
    }
    unsigned int w[32];
#pragma unroll
    for (int i = 0; i < 9; ++i) {
        unsigned int hwv = hu[2 * i] | (hu[2 * i + 1] << 16);
        unsigned int lwv = lu[2 * i] | (lu[2 * i + 1] << 16);
        w[i] = hwv; w[9 + i] = hwv; w[18 + i] = lwv;
    }
#pragma unroll
    for (int i = 27; i < 32; ++i) w[i] = 0;
#pragma unroll
    for (int g = 0; g < 4; ++g) {
        unsigned int* dst = spx + (size_t)kt * 512 + (g * 16 + r) * 8;
        *(uint4*)(dst)     = make_uint4(w[g*4], w[g*4+1], w[g*4+2], w[g*4+3]);
        *(uint4*)(dst + 4) = make_uint4(w[16+g*4], w[16+g*4+1], w[16+g*4+2], w[16+g*4+3]);
    }
}

__global__ __launch_bounds__(512, 4)
void hs_main(const float* __restrict__ x, const float* __restrict__ sp,
             float* __restrict__ out_q, float* __restrict__ out_idx,
             float* __restrict__ ws_scal, const unsigned int* __restrict__ spx,
             float* __restrict__ ws_part, float* __restrict__ ws_kvec)
{
    __shared__ unsigned int xe[RPB][36];     // pixel ext rows [h|l|h|0], 144B stride
    __shared__ float        xsl_lds[RPB][20];// exact fp32 P100-scaled rows
    __shared__ float        zw[NWAVE][RPB];
    __shared__ unsigned int k1w[NWAVE][RPB], k2w[NWAVE][RPB];
    __shared__ float        An_lds[RPB];     // -(P100 + 8 + log2 Z)
    __shared__ float        entw[NWAVE];

    const int tid = threadIdx.x;
    const int l   = tid & 63;                                  // lane
    const int wu  = __builtin_amdgcn_readfirstlane(tid >> 6);  // wave id
    const int col = l & 15, g = l >> 4;
    const int row = blockIdx.x * RPB + l;
    const int b   = row >> 12;
    const int p   = row & 4095;

    // ---- wave 0: load+normalize x rows (P100-scaled); build xe + xsl ----
    if (wu == 0) {
        float xs[D];
        float ssq = 0.f;
#pragma unroll
        for (int j = 0; j < D; ++j) {
            float v = x[(b * D + j) * 4096 + p];
            xs[j] = v;
            ssq += v * v;
        }
        const float sf = (1.0f / sqrtf(ssq)) * P100;
#pragma unroll
        for (int j = 0; j < D; ++j) xs[j] *= sf;
#pragma unroll
        for (int j = 0; j < D; ++j) xsl_lds[l][j] = xs[j];

        unsigned int hu[18], lu[18];
#pragma unroll
        for (int j = 0; j < D; ++j) {
            float res, res2;
            hu[j] = f2bf(xs[j], res);
            lu[j] = f2bf(res, res2);
        }
#pragma unroll
        for (int i = 0; i < 9; ++i) {
            unsigned int hwv = hu[2 * i] | (hu[2 * i + 1] << 16);
            unsigned int lwv = lu[2 * i] | (lu[2 * i + 1] << 16);
            xe[l][i] = hwv; xe[l][9 + i] = lwv; xe[l][18 + i] = hwv;
        }
#pragma unroll
        for (int i = 27; i < 32; ++i) xe[l][i] = 0;
    }
    __syncthreads();

    // ---- loop-invariant X fragments (shared by both sweeps) ----
    union { uint4 u; bf16x8 v; } cv;
    bf16x8 fxlo[4], fxhi[4];
#pragma unroll
    for (int pt = 0; pt < 4; ++pt) {
        cv.u = *(const uint4*)&xe[pt * 16 + col][g * 4];      fxlo[pt] = cv.v;
        cv.u = *(const uint4*)&xe[pt * 16 + col][16 + g * 4]; fxhi[pt] = cv.v;
    }

    // ---- sweep 1 (MFMA): t = P100*s - (P100+8); Z + packed top-2 keys ----
    float Zp[4] = {0.f, 0.f, 0.f, 0.f};
    unsigned int k1p[4] = {0u, 0u, 0u, 0u};
    unsigned int k2p[4] = {0u, 0u, 0u, 0u};
    const int kof = g * 4;
    const int kt0 = wu * KTPW;

#pragma unroll 2
    for (int kt = 0; kt < KTPW; ++kt) {
        const uint4* ap = (const uint4*)(spx + (size_t)(kt0 + kt) * 512 + l * 8);
        cv.u = ap[0]; const bf16x8 alo = cv.v;
        cv.u = ap[1]; const bf16x8 ahi = cv.v;
        const unsigned int inv0 = 4095u - (unsigned int)((kt0 + kt) * 16 + kof);
#pragma unroll
        for (int pt = 0; pt < 4; ++pt) {
            f32x4 c = {SEED1, SEED1, SEED1, SEED1};
            c = __builtin_amdgcn_mfma_f32_16x16x32_bf16(alo, fxlo[pt], c, 0, 0, 0);
            c = __builtin_amdgcn_mfma_f32_16x16x32_bf16(ahi, fxhi[pt], c, 0, 0, 0);
#pragma unroll
            for (int r = 0; r < 4; ++r) {
                const float t = c[r];
                const unsigned int okey = ~__float_as_uint(t);
                const unsigned int key = (okey & 0xFFFFF000u) | (inv0 - (unsigned)r);
                k2p[pt] = max(k2p[pt], min(k1p[pt], key));   // uses old k1p
                k1p[pt] = max(k1p[pt], key);
                Zp[pt] += __builtin_amdgcn_exp2f(t);
            }
        }
    }

    // merge across the 4 g-groups (lanes col, col+16, col+32, col+48)
#pragma unroll
    for (int off = 16; off < 64; off <<= 1) {
#pragma unroll
        for (int pt = 0; pt < 4; ++pt) {
            Zp[pt] += __shfl_xor(Zp[pt], off);
            unsigned int ok1 = (unsigned int)__shfl_xor((int)k1p[pt], off);
            unsigned int ok2 = (unsigned int)__shfl_xor((int)k2p[pt], off);
            k2p[pt] = max(max(k2p[pt], ok2), min(k1p[pt], ok1));
            k1p[pt] = max(k1p[pt], ok1);
        }
    }
    if (g == 0) {
#pragma unroll
        for (int pt = 0; pt < 4; ++pt) {
            const int px = pt * 16 + col;
            zw[wu][px] = Zp[pt];
            k1w[wu][px] = k1p[pt];
            k2w[wu][px] = k2p[pt];
        }
    }
    __syncthreads();

    // ---- wave 0: cross-wave merge + recheck + epilogue ----
    if (wu == 0) {
        float Zt = zw[0][l];
        unsigned int k1 = k1w[0][l], k2 = k2w[0][l];
#pragma unroll
        for (int s = 1; s < NWAVE; ++s) {
            Zt += zw[s][l];
            unsigned int ok1 = k1w[s][l], ok2 = k2w[s][l];
            k2 = max(max(k2, ok2), min(k1, ok1));
            k1 = max(k1, ok1);
        }
        const float l2Z = log2f(Zt);
        An_lds[l] = -(P100 + 8.0f + l2Z);

        float xsl[D];
#pragma unroll
        for (int j = 0; j < D; ++j) xsl[j] = xsl_lds[l][j];

        int i1 = 4095 - (int)(k1 & 0xFFFu);
        int i2 = 4095 - (int)(k2 & 0xFFFu);
        const float tq1 = __uint_as_float(~(k1 | 0xFFFu));
        const float tq2 = __uint_as_float(~(k2 | 0xFFFu));
        int it = i1;
        if (tq1 - tq2 < DELTA) {   // exact fp32 recheck of the two candidates
            const float2* r1 = (const float2*)(sp + i1 * D);
            const float2* r2 = (const float2*)(sp + i2 * D);
            float d1 = 0.f, d2 = 0.f;
#pragma unroll
            for (int j = 0; j < 9; ++j) {
                d1 = fmaf(xsl[2 * j], r1[j].x, d1);
                d1 = fmaf(xsl[2 * j + 1], r1[j].y, d1);
                d2 = fmaf(xsl[2 * j], r2[j].x, d2);
                d2 = fmaf(xsl[2 * j + 1], r2[j].y, d2);
            }
            if (d2 > d1 || (d2 == d1 && i2 < i1)) it = i2;
        }
        out_idx[row] = (float)it;

        // gather chosen codeword (exact fp32); write q; commitment partial
        float2 gq[9];
        const float2* gr = (const float2*)(sp + it * D);
#pragma unroll
        for (int j = 0; j < 9; ++j) gq[j] = gr[j];
        float cp = 0.f;
#pragma unroll
        for (int j = 0; j < 9; ++j) {
            float qx = gq[j].x, qy = gq[j].y;
            float dx = fmaf(xsl[2 * j],     INVP100, -qx);
            float dy = fmaf(xsl[2 * j + 1], INVP100, -qy);
            cp = fmaf(dx, dx, cp);
            cp = fmaf(dy, dy, cp);
            out_q[(b * D + 2 * j)     * 4096 + p] = qx;
            out_q[(b * D + 2 * j + 1) * 4096 + p] = qy;
        }

        float v2 = cp;
#pragma unroll
        for (int off = 1; off < 64; off <<= 1) v2 += __shfl_xor(v2, off);
        if (l == 0) atomicAdd(&ws_scal[1], v2);
    }
    __syncthreads();   // publish An_lds

    // ---- sweep 2 (MFMA, roles swapped): kvec + deferred entropy ----
    // t2 = P100*s + An = log2(prob); E += e*t2 (entropy = -ln2 * E)
    float4 an4[4];
#pragma unroll
    for (int pt = 0; pt < 4; ++pt)
        an4[pt] = *(const float4*)&An_lds[pt * 16 + kof];

    float entacc = 0.f;
    float* pdst = ws_part ? ws_part + (size_t)blockIdx.x * KCB : nullptr;
#pragma unroll 2
    for (int kt = 0; kt < KTPW; ++kt) {
        const uint4* ap = (const uint4*)(spx + (size_t)(kt0 + kt) * 512 + l * 8);
        cv.u = ap[0]; const bf16x8 alo = cv.v;
        cv.u = ap[1]; const bf16x8 ahi = cv.v;

        float ksum = 0.f;
#pragma unroll
        for (int pt = 0; pt < 4; ++pt) {
            f32x4 c = {an4[pt].x, an4[pt].y, an4[pt].z, an4[pt].w};
            c = __builtin_amdgcn_mfma_f32_16x16x32_bf16(fxlo[pt], alo, c, 0, 0, 0);
            c = __builtin_amdgcn_mfma_f32_16x16x32_bf16(fxhi[pt], ahi, c, 0, 0, 0);
#pragma unroll
            for (int r = 0; r < 4; ++r) {
                const float t2 = c[r];
                const float e = __builtin_amdgcn_exp2f(t2);
                ksum += e;
                entacc = fmaf(e, t2, entacc);
            }
        }
        ksum += __shfl_xor(ksum, 16);
        ksum += __shfl_xor(ksum, 32);
        if (g == 0) {
            const int kk = (kt0 + kt) * 16 + col;
            if (pdst) pdst[kk] = ksum;
            else      atomicAdd(&ws_kvec[kk], ksum);
        }
    }

    // block-reduce deferred-entropy partials, one atomic per block
#pragma unroll
    for (int off = 1; off < 64; off <<= 1) entacc += __shfl_xor(entacc, off);
    if (l == 0) entw[wu] = entacc;
    __syncthreads();
    if (tid == 0) {
        float e = 0.f;
#pragma unroll
        for (int s = 0; s < NWAVE; ++s) e += entw[s];
        atomicAdd(&ws_scal[0], e);
    }
}

// Reduce NBLK x KCB partials into kvec (verified r5+).
__global__ void hs_reduce(const float* __restrict__ part, float* __restrict__ kvec)
{
    const int kb = blockIdx.x & 15;
    const int sb = blockIdx.x >> 4;
    const int k  = kb * 256 + threadIdx.x;
    const float* pp = part + (size_t)sb * 32 * KCB + k;
    float s = 0.f;
#pragma unroll 8
    for (int bb = 0; bb < 32; ++bb) s += pp[bb * KCB];
    atomicAdd(&kvec[k], s);
}

__global__ void hs_final(const float* __restrict__ ws_kvec,
                         const float* __restrict__ ws_scal,
                         float* __restrict__ out)
{
    __shared__ float red[4];
    const int tid = threadIdx.x;
    float local = 0.f;
    for (int k = tid; k < KCB; k += 256) {
        float a = ws_kvec[k] * (1.0f / 32768.0f);
        local += a * (log2f(a + 1e-15f) * LN2f);
    }
#pragma unroll
    for (int off = 1; off < 64; off <<= 1) local += __shfl_xor(local, off);
    if ((tid & 63) == 0) red[tid >> 6] = local;
    __syncthreads();
    if (tid == 0) {
        float mean_entro = -(red[0] + red[1] + red[2] + red[3]);
        float entro_mean = -LN2f * ws_scal[0] * (1.0f / 32768.0f);
        float commit     = ws_scal[1] * (1.0f / (32768.0f * 18.0f));
        out[SCL_OFF + 0] = entro_mean;
        out[SCL_OFF + 1] = mean_entro;
        out[SCL_OFF + 2] = entro_mean - mean_entro;
        out[SCL_OFF + 3] = commit;
    }
}

extern "C" void kernel_launch(void* const* d_in, const int* in_sizes, int n_in,
                              void* d_out, int out_size, void* d_ws, size_t ws_size,
                              hipStream_t stream)
{
    const float* x  = (const float*)d_in[0];
    const float* sp = (const float*)d_in[1];
    float* out = (float*)d_out;
    float* ws  = (float*)d_ws;

    const bool partials = ws_size >= (size_t)WS_END * sizeof(float);

    hipMemsetAsync(ws, 0, (WS_KVEC + KCB) * sizeof(float), stream);

    hs_prep<<<16, 256, 0, stream>>>(sp, (unsigned int*)(ws + WS_SPEXT));
    hs_main<<<NBLK, 512, 0, stream>>>(x, sp, out + Q_OFF, out + IDX_OFF,
                                      ws + WS_SCAL,
                                      (const unsigned int*)(ws + WS_SPEXT),
                                      partials ? ws + WS_PART : nullptr,
                                      ws + WS_KVEC);
    if (partials)
        hs_reduce<<<256, 256, 0, stream>>>(ws + WS_PART, ws + WS_KVEC);
    hs_final<<<1, 256, 0, stream>>>(ws + WS_KVEC, ws + WS_SCAL, out);
}